// Round 7
// baseline (196.988 us; speedup 1.0000x reference)
//
#include <hip/hip_runtime.h>
#include <hip/hip_bf16.h>
#include <stdint.h>

// B=4, C=256, N=4096, dk=32
typedef float f32x16 __attribute__((ext_vector_type(16)));
typedef short bf16x8 __attribute__((ext_vector_type(8)));

#define L2E 1.4426950408889634f
#define ROWPAT(r, hi) (((r) & 3) + 8 * ((r) >> 2) + 4 * (hi))

// ws layout (bytes)
#define WCATB_OFF 0u
#define XT_OFF    163840u
#define QBUF_OFF  8552448u
#define KBUF_OFF  9601024u
#define VBUF_OFF  10649600u

static __device__ __forceinline__ ushort f2bf(float f) {
    union { float f; uint32_t u; } v; v.f = f;
    uint32_t u = v.u;
    return (ushort)((u + 0x7fffu + ((u >> 16) & 1u)) >> 16);
}

static __device__ __forceinline__ uint32_t cvtpk(float lo, float hi) {
    uint32_t r;
    asm volatile("v_cvt_pk_bf16_f32 %0, %1, %2" : "=v"(r) : "v"(lo), "v"(hi));
    return r;
}
// p[j] at D-pattern m' = (j&3)+8*(j>>2)+4*hi; -> B-frag words for 16 keys.
static __device__ __forceinline__ uint4 packP(float p0, float p1, float p2, float p3,
                                              float p4, float p5, float p6, float p7) {
    uint32_t a0 = cvtpk(p0, p1), a1 = cvtpk(p2, p3);
    uint32_t b0 = cvtpk(p4, p5), b1 = cvtpk(p6, p7);
    auto s0 = __builtin_amdgcn_permlane32_swap(a0, b0, false, false);
    auto s1 = __builtin_amdgcn_permlane32_swap(a1, b1, false, false);
    uint4 pk;
    pk.x = s0[0];
    pk.y = s1[0];
    pk.z = s0[1];
    pk.w = s1[1];
    return pk;
}

// ---------------- prep: Wcat_bf16 [320][256] ----------------
__global__ void prep_kernel(const float* __restrict__ Wq, const float* __restrict__ Wk,
                            const float* __restrict__ Wv, ushort* __restrict__ Wcb) {
    int row = blockIdx.x, c = threadIdx.x;
    float v;
    if (row < 32)      v = Wq[row * 256 + c];
    else if (row < 64) v = Wk[(row - 32) * 256 + c];
    else               v = Wv[(row - 64) * 256 + c];
    Wcb[row * 256 + c] = f2bf(v);
}

// ---------------- x transpose: f32 [b][c][n] -> bf16 xT [b][n][256] ----------
__global__ __launch_bounds__(256)
void xt_kernel(const float* __restrict__ x, ushort* __restrict__ xT) {
    __shared__ ushort t[64][80];
    const int tid = threadIdx.x;
    const int b = blockIdx.x >> 8;
    const int c0 = ((blockIdx.x >> 6) & 3) << 6;
    const int n0 = (blockIdx.x & 63) << 6;
    const float* xb = x + ((size_t)(b * 256 + c0)) * 4096 + n0;
    #pragma unroll
    for (int p = 0; p < 4; ++p) {
        int cl = (tid >> 4) + p * 16;
        int nl = (tid & 15) * 4;
        float4 v = *(const float4*)(xb + (size_t)cl * 4096 + nl);
        t[nl + 0][cl] = f2bf(v.x);
        t[nl + 1][cl] = f2bf(v.y);
        t[nl + 2][cl] = f2bf(v.z);
        t[nl + 3][cl] = f2bf(v.w);
    }
    __syncthreads();
    ushort* xo = xT + ((size_t)(b * 4096 + n0)) * 256 + c0;
    #pragma unroll
    for (int p = 0; p < 2; ++p) {
        int idx = tid + (p << 8);
        int nl = idx >> 3, sg = idx & 7;
        *(uint4*)(xo + (size_t)nl * 256 + sg * 8) = *(const uint4*)&t[nl][sg * 8];
    }
}

// ---------------- proj Q,K: store [b][n][32] bf16; grid 256 ------------------
__global__ __launch_bounds__(256)
void proj_qk_kernel(const ushort* __restrict__ xT, const ushort* __restrict__ Wcb,
                    const float* __restrict__ bq, const float* __restrict__ bk,
                    ushort* __restrict__ qbuf, ushort* __restrict__ kbuf) {
    const int tid = threadIdx.x;
    const int w = tid >> 6, l31 = tid & 31, hi = (tid & 63) >> 5;
    const int b = blockIdx.x >> 6;
    const int nt = (blockIdx.x & 63) * 2 + (w & 1);
    const int isK = w >> 1;

    const ushort* xrow = xT + ((size_t)(b * 4096 + nt * 32 + l31)) * 256;
    const ushort* wrow = Wcb + (size_t)(isK * 32 + l31) * 256;

    f32x16 acc = (f32x16)0.0f;
    #pragma unroll
    for (int kk = 0; kk < 16; ++kk) {
        bf16x8 af = *(const bf16x8*)&xrow[kk * 16 + hi * 8];
        bf16x8 bf8 = *(const bf16x8*)&wrow[kk * 16 + hi * 8];
        acc = __builtin_amdgcn_mfma_f32_32x32x16_bf16(af, bf8, acc, 0, 0, 0);
    }
    const float bias = isK ? bk[l31] : bq[l31];
    ushort* dst = isK ? kbuf : qbuf;
    #pragma unroll
    for (int r = 0; r < 16; ++r) {
        int n = nt * 32 + ROWPAT(r, hi);
        dst[((size_t)((b << 12) + n)) * 32 + l31] = f2bf(acc[r] + bias);
    }
}

// ---------------- proj V: store [b][c][n] bf16 ------------------------------
__global__ __launch_bounds__(256)
void proj_v_kernel(const ushort* __restrict__ xT, const ushort* __restrict__ Wcb,
                   const float* __restrict__ bv, ushort* __restrict__ vbuf) {
    const int tid = threadIdx.x;
    const int w = tid >> 6, l31 = tid & 31, hi = (tid & 63) >> 5;
    const int b = blockIdx.x >> 8;
    const int ct = (blockIdx.x >> 5) & 7;
    const int nt = (blockIdx.x & 31) * 4 + w;

    const ushort* wv = Wcb + (size_t)(64 + ct * 32 + l31) * 256;
    const ushort* xrow = xT + ((size_t)(b * 4096 + nt * 32 + l31)) * 256;

    f32x16 acc = (f32x16)0.0f;
    #pragma unroll
    for (int kk = 0; kk < 16; ++kk) {
        bf16x8 af = *(const bf16x8*)&wv[kk * 16 + hi * 8];
        bf16x8 bf8 = *(const bf16x8*)&xrow[kk * 16 + hi * 8];
        acc = __builtin_amdgcn_mfma_f32_32x32x16_bf16(af, bf8, acc, 0, 0, 0);
    }
    #pragma unroll
    for (int r = 0; r < 16; ++r) {
        int c = ct * 32 + ROWPAT(r, hi);
        vbuf[((size_t)(b * 256 + c)) * 4096 + nt * 32 + l31] = f2bf(acc[r] + bv[c]);
    }
}

// ---------------- attention v5: producer/consumer wave roles -----------------
// grid 256 (XCD-swizzled) = 4b x 64 qtiles(64q); block 512 = 8 waves.
// QK waves w=0..3 (qt=w>>1, kh=w&1): sT=mfma(K,Q), exp, packP -> plds (dbuf).
// PV waves w=4..7 (qt, cp=w&1): read P+V frags, 16 MFMA/iter, own 128c x 32q.
// PV lags QK by one tile: V triple-buffered, K/P double-buffered, 1 barrier/iter.
// Each exp computed exactly once (R5/R6 computed each 2x/4x).
#define KSTR 40
#define VSTR 72
__global__ __launch_bounds__(512)
void attn_kernel(const ushort* __restrict__ qbuf, const ushort* __restrict__ kbuf,
                 const ushort* __restrict__ vbuf, const float* __restrict__ x,
                 const float* __restrict__ gammap, float* __restrict__ out) {
    __shared__ ushort klds[2][64 * KSTR];   // 10 KB
    __shared__ ushort vlds[3][256 * VSTR];  // 108 KB
    __shared__ uint4  plds[2 * 2 * 2 * 2 * 64];  // [buf][qt][kh][f][lane], 16 KB
    __shared__ float  dlds[2][2][32];

    const int tid = threadIdx.x;
    const int bid = blockIdx.x;
    const int work = (bid & 7) * 32 + (bid >> 3);   // XCD-cluster: one batch per XCD
    const int b = work >> 6;
    const int qbase = (work & 63) << 6;
    const int w = tid >> 6, l = tid & 63;
    const int l31 = l & 31, hi = l >> 5;
    const bool isQK = (w < 4);
    const int qt = isQK ? (w >> 1) : ((w - 4) >> 1);
    const int khcp = w & 1;   // kh for QK waves, cp for PV waves

    const ushort* kb = kbuf + ((size_t)b << 12) * 32;
    const ushort* vb = vbuf + ((size_t)b << 8) * 4096;

    // Q B-frags (used by QK waves; col=q=qt*32+l31, k = 16*kst + 8*hi + j)
    const ushort* qrow = qbuf + ((size_t)((b << 12) + qbase + qt * 32 + l31)) * 32;
    const bf16x8 qf0 = *(const bf16x8*)&qrow[hi * 8];
    const bf16x8 qf1 = *(const bf16x8*)&qrow[16 + hi * 8];

    f32x16 acc[4];
    #pragma unroll
    for (int ch = 0; ch < 4; ++ch) acc[ch] = (f32x16)0.0f;
    float dsum = 0.f;

    // staging (all 512 threads): V 256x64 (32KB), K 64x32 (4KB)
    const int vc = tid >> 3, vs = tid & 7;
    const int krow = tid >> 2, kseg = tid & 3;
    const ushort* vsrc = vb + (size_t)vc * 4096 + vs * 8;
    const ushort* ksrc = kb + (size_t)krow * 32 + kseg * 8;
    uint4 vreg[4], kreg;

    // prologue: stage tile 0 -> K[0], V[0]
    #pragma unroll
    for (int i = 0; i < 4; ++i)
        vreg[i] = *(const uint4*)(vsrc + (size_t)i * 64 * 4096);
    if (tid < 256) kreg = *(const uint4*)ksrc;
    #pragma unroll
    for (int i = 0; i < 4; ++i)
        *(uint4*)&vlds[0][(vc + 64 * i) * VSTR + vs * 8] = vreg[i];
    if (tid < 256) *(uint4*)&klds[0][krow * KSTR + kseg * 8] = kreg;
    __syncthreads();

    int vw = 1, vr = 2;   // V write idx = (it+1)%3, V read idx = (it-1)%3
    for (int it = 0; it <= 64; ++it) {
        const int cur = it & 1;

        // issue prefetch for tile it+1 (consumed: K at it+1, V at it+2)
        if (it < 63) {
            const size_t m0 = (size_t)(it + 1) << 6;
            #pragma unroll
            for (int i = 0; i < 4; ++i)
                vreg[i] = *(const uint4*)(vsrc + (size_t)i * 64 * 4096 + m0);
            if (tid < 256) kreg = *(const uint4*)(ksrc + (m0 << 5));
        }

        if (isQK) {
            if (it < 64) {
                // sT[key][q] for keys kh*32 + ROWPAT(r,hi)
                const int krow_a = (khcp * 32 + l31) * KSTR;
                bf16x8 kf0 = *(const bf16x8*)&klds[cur][krow_a + hi * 8];
                bf16x8 kf1 = *(const bf16x8*)&klds[cur][krow_a + 16 + hi * 8];
                f32x16 sT = __builtin_amdgcn_mfma_f32_32x32x16_bf16(kf0, qf0, (f32x16)0.0f, 0, 0, 0);
                sT = __builtin_amdgcn_mfma_f32_32x32x16_bf16(kf1, qf1, sT, 0, 0, 0);

                float p[16];
                #pragma unroll
                for (int r = 0; r < 16; ++r) {
                    p[r] = exp2f(sT[r] * L2E);
                    dsum += p[r];
                }
                uint4 w0 = packP(p[0], p[1], p[2], p[3], p[4], p[5], p[6], p[7]);
                uint4 w1 = packP(p[8], p[9], p[10], p[11], p[12], p[13], p[14], p[15]);
                uint4* pb = &plds[(((cur * 2 + qt) * 2 + khcp) * 2) * 64];
                pb[l] = w0;
                pb[64 + l] = w1;
            } else {
                // final: publish denominators
                float dall = dsum + __shfl_xor(dsum, 32);
                if (l < 32) dlds[qt][khcp][l31] = dall;
            }
        } else {
            if (it >= 1) {
                // consume tile it-1: P from plds[cur^1], V from vlds[vr]
                const uint4* pb = &plds[(((cur ^ 1) * 2 + qt) * 2) * 2 * 64];
                union { uint4 u; bf16x8 v; } pf[4];
                pf[0].u = pb[l];            // kh0, k 0..15
                pf[1].u = pb[64 + l];       // kh0, k 16..31
                pf[2].u = pb[128 + l];      // kh1, k 32..47
                pf[3].u = pb[192 + l];      // kh1, k 48..63
                const ushort* vt = &vlds[vr][0];
                #pragma unroll
                for (int ch = 0; ch < 4; ++ch) {
                    const int crow = (khcp * 128 + ch * 32 + l31) * VSTR;
                    bf16x8 vfa = *(const bf16x8*)&vt[crow + hi * 8];
                    bf16x8 vfb = *(const bf16x8*)&vt[crow + 16 + hi * 8];
                    bf16x8 vfc = *(const bf16x8*)&vt[crow + 32 + hi * 8];
                    bf16x8 vfd = *(const bf16x8*)&vt[crow + 48 + hi * 8];
                    acc[ch] = __builtin_amdgcn_mfma_f32_32x32x16_bf16(vfa, pf[0].v, acc[ch], 0, 0, 0);
                    acc[ch] = __builtin_amdgcn_mfma_f32_32x32x16_bf16(vfb, pf[1].v, acc[ch], 0, 0, 0);
                    acc[ch] = __builtin_amdgcn_mfma_f32_32x32x16_bf16(vfc, pf[2].v, acc[ch], 0, 0, 0);
                    acc[ch] = __builtin_amdgcn_mfma_f32_32x32x16_bf16(vfd, pf[3].v, acc[ch], 0, 0, 0);
                }
            }
        }

        // write staged tile it+1 -> K[cur^1], V[vw]
        if (it < 63) {
            #pragma unroll
            for (int i = 0; i < 4; ++i)
                *(uint4*)&vlds[vw][(vc + 64 * i) * VSTR + vs * 8] = vreg[i];
            if (tid < 256) *(uint4*)&klds[cur ^ 1][krow * KSTR + kseg * 8] = kreg;
        }
        if (it < 64) __syncthreads();
        vw = (vw == 2) ? 0 : vw + 1;
        vr = (vr == 2) ? 0 : vr + 1;
    }

    __syncthreads();   // dlds visible

    if (!isQK) {
        const float gam = gammap[0];
        const float denom = dlds[qt][0][l31] + dlds[qt][1][l31];
        const float ginv = gam / denom;
        const float* xb2 = x + (((size_t)b) << 8) * 4096;
        float* ob = out + (((size_t)b) << 8) * 4096;
        const int q = qbase + qt * 32 + l31;
        #pragma unroll
        for (int ch = 0; ch < 4; ++ch) {
            #pragma unroll
            for (int r = 0; r < 16; ++r) {
                int c = khcp * 128 + ch * 32 + ROWPAT(r, hi);
                size_t idx = (size_t)c * 4096 + q;
                ob[idx] = acc[ch][r] * ginv + xb2[idx];
            }
        }
    }
}

extern "C" void kernel_launch(void* const* d_in, const int* in_sizes, int n_in,
                              void* d_out, int out_size, void* d_ws, size_t ws_size,
                              hipStream_t stream) {
    (void)in_sizes; (void)n_in; (void)out_size; (void)ws_size;
    const float* x     = (const float*)d_in[0];
    const float* Wq    = (const float*)d_in[1];
    const float* bq    = (const float*)d_in[2];
    const float* Wk    = (const float*)d_in[3];
    const float* bk    = (const float*)d_in[4];
    const float* Wv    = (const float*)d_in[5];
    const float* bv    = (const float*)d_in[6];
    const float* gamma = (const float*)d_in[7];
    float* out = (float*)d_out;

    char* ws = (char*)d_ws;
    ushort* Wcb  = (ushort*)(ws + WCATB_OFF);
    ushort* xT   = (ushort*)(ws + XT_OFF);
    ushort* qbuf = (ushort*)(ws + QBUF_OFF);
    ushort* kbuf = (ushort*)(ws + KBUF_OFF);
    ushort* vbuf = (ushort*)(ws + VBUF_OFF);

    prep_kernel<<<320, 256, 0, stream>>>(Wq, Wk, Wv, Wcb);
    xt_kernel<<<1024, 256, 0, stream>>>(x, xT);
    proj_qk_kernel<<<256, 256, 0, stream>>>(xT, Wcb, bq, bk, qbuf, kbuf);
    proj_v_kernel<<<1024, 256, 0, stream>>>(xT, Wcb, bv, vbuf);
    attn_kernel<<<256, 512, 0, stream>>>(qbuf, kbuf, vbuf, x, gamma, out);
}

// Round 8
// 121.190 us; speedup vs baseline: 1.6254x; 1.6254x over previous
//
#include <hip/hip_runtime.h>
#include <hip/hip_bf16.h>
#include <stdint.h>

// B=4, C=256, N=4096, dk=32
typedef float f32x16 __attribute__((ext_vector_type(16)));
typedef short bf16x8 __attribute__((ext_vector_type(8)));

#define L2E 1.4426950408889634f
#define ROWPAT(r, hi) (((r) & 3) + 8 * ((r) >> 2) + 4 * (hi))

// ws layout (bytes)
#define WCATB_OFF 0u
#define XT_OFF    163840u
#define QBUF_OFF  8552448u
#define KBUF_OFF  9601024u
#define VBUF_OFF  10649600u

static __device__ __forceinline__ ushort f2bf(float f) {
    union { float f; uint32_t u; } v; v.f = f;
    uint32_t u = v.u;
    return (ushort)((u + 0x7fffu + ((u >> 16) & 1u)) >> 16);
}

static __device__ __forceinline__ uint32_t cvtpk(float lo, float hi) {
    uint32_t r;
    asm volatile("v_cvt_pk_bf16_f32 %0, %1, %2" : "=v"(r) : "v"(lo), "v"(hi));
    return r;
}
// p[j] at D-pattern m' = (j&3)+8*(j>>2)+4*hi; -> B-frag words for 16 keys.
static __device__ __forceinline__ bf16x8 packP(float p0, float p1, float p2, float p3,
                                               float p4, float p5, float p6, float p7) {
    uint32_t a0 = cvtpk(p0, p1), a1 = cvtpk(p2, p3);
    uint32_t b0 = cvtpk(p4, p5), b1 = cvtpk(p6, p7);
    auto s0 = __builtin_amdgcn_permlane32_swap(a0, b0, false, false);
    auto s1 = __builtin_amdgcn_permlane32_swap(a1, b1, false, false);
    union { uint32_t u[4]; bf16x8 v; } pk;
    pk.u[0] = s0[0];
    pk.u[1] = s1[0];
    pk.u[2] = s0[1];
    pk.u[3] = s1[1];
    return pk.v;
}

// ---------------- prep: Wcat_bf16 [320][256] ----------------
__global__ void prep_kernel(const float* __restrict__ Wq, const float* __restrict__ Wk,
                            const float* __restrict__ Wv, ushort* __restrict__ Wcb) {
    int row = blockIdx.x, c = threadIdx.x;
    float v;
    if (row < 32)      v = Wq[row * 256 + c];
    else if (row < 64) v = Wk[(row - 32) * 256 + c];
    else               v = Wv[(row - 64) * 256 + c];
    Wcb[row * 256 + c] = f2bf(v);
}

// ---------------- x transpose: f32 [b][c][n] -> bf16 xT [b][n][256] ----------
__global__ __launch_bounds__(256)
void xt_kernel(const float* __restrict__ x, ushort* __restrict__ xT) {
    __shared__ ushort t[64][80];
    const int tid = threadIdx.x;
    const int b = blockIdx.x >> 8;
    const int c0 = ((blockIdx.x >> 6) & 3) << 6;
    const int n0 = (blockIdx.x & 63) << 6;
    const float* xb = x + ((size_t)(b * 256 + c0)) * 4096 + n0;
    #pragma unroll
    for (int p = 0; p < 4; ++p) {
        int cl = (tid >> 4) + p * 16;
        int nl = (tid & 15) * 4;
        float4 v = *(const float4*)(xb + (size_t)cl * 4096 + nl);
        t[nl + 0][cl] = f2bf(v.x);
        t[nl + 1][cl] = f2bf(v.y);
        t[nl + 2][cl] = f2bf(v.z);
        t[nl + 3][cl] = f2bf(v.w);
    }
    __syncthreads();
    ushort* xo = xT + ((size_t)(b * 4096 + n0)) * 256 + c0;
    #pragma unroll
    for (int p = 0; p < 2; ++p) {
        int idx = tid + (p << 8);
        int nl = idx >> 3, sg = idx & 7;
        *(uint4*)(xo + (size_t)nl * 256 + sg * 8) = *(const uint4*)&t[nl][sg * 8];
    }
}

// ---------------- proj Q,K: store [b][n][32] bf16; Q pre-scaled by log2(e) ---
__global__ __launch_bounds__(256)
void proj_qk_kernel(const ushort* __restrict__ xT, const ushort* __restrict__ Wcb,
                    const float* __restrict__ bq, const float* __restrict__ bk,
                    ushort* __restrict__ qbuf, ushort* __restrict__ kbuf) {
    const int tid = threadIdx.x;
    const int w = tid >> 6, l31 = tid & 31, hi = (tid & 63) >> 5;
    const int b = blockIdx.x >> 6;
    const int nt = (blockIdx.x & 63) * 2 + (w & 1);
    const int isK = w >> 1;

    const ushort* xrow = xT + ((size_t)(b * 4096 + nt * 32 + l31)) * 256;
    const ushort* wrow = Wcb + (size_t)(isK * 32 + l31) * 256;

    f32x16 acc = (f32x16)0.0f;
    #pragma unroll
    for (int kk = 0; kk < 16; ++kk) {
        bf16x8 af = *(const bf16x8*)&xrow[kk * 16 + hi * 8];
        bf16x8 bf8 = *(const bf16x8*)&wrow[kk * 16 + hi * 8];
        acc = __builtin_amdgcn_mfma_f32_32x32x16_bf16(af, bf8, acc, 0, 0, 0);
    }
    const float bias = isK ? bk[l31] : bq[l31];
    const float scale = isK ? 1.0f : L2E;   // fold log2(e) into Q
    ushort* dst = isK ? kbuf : qbuf;
    #pragma unroll
    for (int r = 0; r < 16; ++r) {
        int n = nt * 32 + ROWPAT(r, hi);
        dst[((size_t)((b << 12) + n)) * 32 + l31] = f2bf((acc[r] + bias) * scale);
    }
}

// ---------------- proj V: store [b][c][n] bf16 ------------------------------
__global__ __launch_bounds__(256)
void proj_v_kernel(const ushort* __restrict__ xT, const ushort* __restrict__ Wcb,
                   const float* __restrict__ bv, ushort* __restrict__ vbuf) {
    const int tid = threadIdx.x;
    const int w = tid >> 6, l31 = tid & 31, hi = (tid & 63) >> 5;
    const int b = blockIdx.x >> 8;
    const int ct = (blockIdx.x >> 5) & 7;
    const int nt = (blockIdx.x & 31) * 4 + w;

    const ushort* wv = Wcb + (size_t)(64 + ct * 32 + l31) * 256;
    const ushort* xrow = xT + ((size_t)(b * 4096 + nt * 32 + l31)) * 256;

    f32x16 acc = (f32x16)0.0f;
    #pragma unroll
    for (int kk = 0; kk < 16; ++kk) {
        bf16x8 af = *(const bf16x8*)&wv[kk * 16 + hi * 8];
        bf16x8 bf8 = *(const bf16x8*)&xrow[kk * 16 + hi * 8];
        acc = __builtin_amdgcn_mfma_f32_32x32x16_bf16(af, bf8, acc, 0, 0, 0);
    }
    #pragma unroll
    for (int r = 0; r < 16; ++r) {
        int c = ct * 32 + ROWPAT(r, hi);
        vbuf[((size_t)(b * 256 + c)) * 4096 + nt * 32 + l31] = f2bf(acc[r] + bv[c]);
    }
}

// ---------------- attention v6: R5 per-wave workload, decoupled 4-wave blocks
// grid 512 (XCD-clustered) = 4b x 128 qtiles(32q); block 256 = 4 waves.
// wave w: kh=w>>1 (32 keys), cp=w&1 (128 channels, 4 chunks). Full coverage:
// cp(2) x 128ch x 32q. exp dup x2 (kh pairs share nothing; cp pairs dup QK) —
// same total VALU as R5. LDS 77KB -> 2 blocks/CU, independent barriers.
#define KSTR 36
#define VSTR 66
__global__ __launch_bounds__(256, 2)
void attn_kernel(const ushort* __restrict__ qbuf, const ushort* __restrict__ kbuf,
                 const ushort* __restrict__ vbuf, const float* __restrict__ x,
                 const float* __restrict__ gammap, float* __restrict__ out) {
    __shared__ ushort klds[2][64 * KSTR];   // 9 KB
    __shared__ ushort vlds[2][256 * VSTR];  // 66 KB (reused as 32KB f32 scratch)
    __shared__ float  dlds[2][32];

    const int tid = threadIdx.x;
    const int bid = blockIdx.x;
    const int work = (bid & 7) * 64 + (bid >> 3);   // XCD-cluster: one batch per 2 XCDs
    const int b = work >> 7;
    const int qbase = (work & 127) << 5;
    const int w = tid >> 6, l = tid & 63;
    const int l31 = l & 31, hi = l >> 5;
    const int kh = w >> 1, cp = w & 1;

    const ushort* kb = kbuf + ((size_t)b << 12) * 32;
    const ushort* vb = vbuf + ((size_t)b << 8) * 4096;

    // Q B-frags (col=q=l31 of this 32q tile, k = 16*kst + 8*hi + j)
    const ushort* qrow = qbuf + ((size_t)((b << 12) + qbase + l31)) * 32;
    const bf16x8 qf0 = *(const bf16x8*)&qrow[hi * 8];
    const bf16x8 qf1 = *(const bf16x8*)&qrow[16 + hi * 8];

    f32x16 acc[4];
    #pragma unroll
    for (int ch = 0; ch < 4; ++ch) acc[ch] = (f32x16)0.0f;
    float dsum = 0.f;

    // staging (256 thr): V 256x64 (32KB) via 8 uint4, K 64x32 (4KB) via 1 uint4
    const int vc = tid >> 3, vs = tid & 7;      // V rows vc+32i, 16B seg vs
    const int krow = tid >> 2, kseg = tid & 3;  // K row, 16B seg
    const ushort* vsrc = vb + (size_t)vc * 4096 + vs * 8;
    const ushort* ksrc = kb + (size_t)krow * 32 + kseg * 8;
    uint4 vreg[8], kreg;

    // prologue: stage tile 0 -> buf 0
    #pragma unroll
    for (int i = 0; i < 8; ++i)
        vreg[i] = *(const uint4*)(vsrc + (size_t)i * 32 * 4096);
    kreg = *(const uint4*)ksrc;
    #pragma unroll
    for (int i = 0; i < 8; ++i)
        *(uint4*)&vlds[0][(vc + 32 * i) * VSTR + vs * 8] = vreg[i];
    *(uint4*)&klds[0][krow * KSTR + kseg * 8] = kreg;
    __syncthreads();

    for (int it = 0; it < 64; ++it) {
        const int cur = it & 1;
        // issue prefetch for tile it+1
        if (it < 63) {
            const size_t m0 = (size_t)(it + 1) << 6;
            #pragma unroll
            for (int i = 0; i < 8; ++i)
                vreg[i] = *(const uint4*)(vsrc + (size_t)i * 32 * 4096 + m0);
            kreg = *(const uint4*)(ksrc + (m0 << 5));
        }

        // QK^T swapped: sT[key][q], keys = kh*32 + ROWPAT(r,hi); Q pre-scaled by L2E
        const int krow_a = (kh * 32 + l31) * KSTR;
        bf16x8 kf0 = *(const bf16x8*)&klds[cur][krow_a + hi * 8];
        bf16x8 kf1 = *(const bf16x8*)&klds[cur][krow_a + 16 + hi * 8];
        f32x16 sT = __builtin_amdgcn_mfma_f32_32x32x16_bf16(kf0, qf0, (f32x16)0.0f, 0, 0, 0);
        sT = __builtin_amdgcn_mfma_f32_32x32x16_bf16(kf1, qf1, sT, 0, 0, 0);

        // exp2 directly (scale folded into Q); no-max softmax
        float p[16];
        #pragma unroll
        for (int r = 0; r < 16; ++r) {
            p[r] = exp2f(sT[r]);
            dsum += p[r];
        }
        bf16x8 pf0 = packP(p[0], p[1], p[2], p[3], p[4], p[5], p[6], p[7]);
        bf16x8 pf1 = packP(p[8], p[9], p[10], p[11], p[12], p[13], p[14], p[15]);

        // PV: acc^T[c][q] += V x P over this kh's 32 keys; 4 chunks = 128 channels
        __builtin_amdgcn_s_setprio(1);
        #pragma unroll
        for (int ch = 0; ch < 4; ++ch) {
            const int crow = (cp * 128 + ch * 32 + l31) * VSTR + kh * 32;
            bf16x8 vfa = *(const bf16x8*)&vlds[cur][crow + hi * 8];
            bf16x8 vfb = *(const bf16x8*)&vlds[cur][crow + 16 + hi * 8];
            acc[ch] = __builtin_amdgcn_mfma_f32_32x32x16_bf16(vfa, pf0, acc[ch], 0, 0, 0);
            acc[ch] = __builtin_amdgcn_mfma_f32_32x32x16_bf16(vfb, pf1, acc[ch], 0, 0, 0);
        }
        __builtin_amdgcn_s_setprio(0);

        // write prefetched tile to the other buffer
        if (it < 63) {
            const int nb = cur ^ 1;
            #pragma unroll
            for (int i = 0; i < 8; ++i)
                *(uint4*)&vlds[nb][(vc + 32 * i) * VSTR + vs * 8] = vreg[i];
            *(uint4*)&klds[nb][krow * KSTR + kseg * 8] = kreg;
        }
        __syncthreads();
    }

    // ---- cross-kh combine + epilogue ----
    const float gam = gammap[0];
    float dall = dsum + __shfl_xor(dsum, 32);
    float* scr = (float*)&vlds[0][0];   // 32 KB scratch ([cp*4+ch][r] x [lane])
    if (kh == 1) {
        #pragma unroll
        for (int ch = 0; ch < 4; ++ch)
            #pragma unroll
            for (int r = 0; r < 16; ++r)
                scr[(((cp * 4 + ch) * 16 + r) << 6) + l] = acc[ch][r];
    }
    if (cp == 0 && l < 32) dlds[kh][l31] = dall;
    __syncthreads();
    if (kh == 0) {
        const float denom = dlds[0][l31] + dlds[1][l31];
        const float ginv = gam / denom;
        const float* xb2 = x + (((size_t)b) << 8) * 4096;
        float* ob = out + (((size_t)b) << 8) * 4096;
        const int q = qbase + l31;
        #pragma unroll
        for (int ch = 0; ch < 4; ++ch) {
            #pragma unroll
            for (int r = 0; r < 16; ++r) {
                int c = cp * 128 + ch * 32 + ROWPAT(r, hi);
                float o = acc[ch][r] + scr[(((cp * 4 + ch) * 16 + r) << 6) + l];
                size_t idx = (size_t)c * 4096 + q;
                ob[idx] = o * ginv + xb2[idx];
            }
        }
    }
}

extern "C" void kernel_launch(void* const* d_in, const int* in_sizes, int n_in,
                              void* d_out, int out_size, void* d_ws, size_t ws_size,
                              hipStream_t stream) {
    (void)in_sizes; (void)n_in; (void)out_size; (void)ws_size;
    const float* x     = (const float*)d_in[0];
    const float* Wq    = (const float*)d_in[1];
    const float* bq    = (const float*)d_in[2];
    const float* Wk    = (const float*)d_in[3];
    const float* bk    = (const float*)d_in[4];
    const float* Wv    = (const float*)d_in[5];
    const float* bv    = (const float*)d_in[6];
    const float* gamma = (const float*)d_in[7];
    float* out = (float*)d_out;

    char* ws = (char*)d_ws;
    ushort* Wcb  = (ushort*)(ws + WCATB_OFF);
    ushort* xT   = (ushort*)(ws + XT_OFF);
    ushort* qbuf = (ushort*)(ws + QBUF_OFF);
    ushort* kbuf = (ushort*)(ws + KBUF_OFF);
    ushort* vbuf = (ushort*)(ws + VBUF_OFF);

    prep_kernel<<<320, 256, 0, stream>>>(Wq, Wk, Wv, Wcb);
    xt_kernel<<<1024, 256, 0, stream>>>(x, xT);
    proj_qk_kernel<<<256, 256, 0, stream>>>(xT, Wcb, bq, bk, qbuf, kbuf);
    proj_v_kernel<<<1024, 256, 0, stream>>>(xT, Wcb, bv, vbuf);
    attn_kernel<<<512, 256, 0, stream>>>(qbuf, kbuf, vbuf, x, gamma, out);
}

// Round 10
// 111.990 us; speedup vs baseline: 1.7590x; 1.0822x over previous
//
#include <hip/hip_runtime.h>
#include <hip/hip_bf16.h>
#include <stdint.h>

// B=4, C=256, N=4096, dk=32
typedef float f32x16 __attribute__((ext_vector_type(16)));
typedef short bf16x8 __attribute__((ext_vector_type(8)));

#define L2E 1.4426950408889634f
#define ROWPAT(r, hi) (((r) & 3) + 8 * ((r) >> 2) + 4 * (hi))

// ws layout (bytes): Wcb 160KB | qbuf 1MB | kbuf 1MB | vbuf 8MB
#define WCATB_OFF 0u
#define QBUF_OFF  163840u
#define KBUF_OFF  1212416u
#define VBUF_OFF  2260992u

static __device__ __forceinline__ ushort f2bf(float f) {
    union { float f; uint32_t u; } v; v.f = f;
    uint32_t u = v.u;
    return (ushort)((u + 0x7fffu + ((u >> 16) & 1u)) >> 16);
}

static __device__ __forceinline__ uint32_t cvtpk(float lo, float hi) {
    uint32_t r;
    asm volatile("v_cvt_pk_bf16_f32 %0, %1, %2" : "=v"(r) : "v"(lo), "v"(hi));
    return r;
}
// p[j] at D-pattern m' = (j&3)+8*(j>>2)+4*hi; -> B-frag words for 16 keys.
static __device__ __forceinline__ bf16x8 packP(float p0, float p1, float p2, float p3,
                                               float p4, float p5, float p6, float p7) {
    uint32_t a0 = cvtpk(p0, p1), a1 = cvtpk(p2, p3);
    uint32_t b0 = cvtpk(p4, p5), b1 = cvtpk(p6, p7);
    auto s0 = __builtin_amdgcn_permlane32_swap(a0, b0, false, false);
    auto s1 = __builtin_amdgcn_permlane32_swap(a1, b1, false, false);
    union { uint32_t u[4]; bf16x8 v; } pk;
    pk.u[0] = s0[0];
    pk.u[1] = s1[0];
    pk.u[2] = s0[1];
    pk.u[3] = s1[1];
    return pk.v;
}

// ---------------- prep: Wcat_bf16 [320][256] ----------------
__global__ void prep_kernel(const float* __restrict__ Wq, const float* __restrict__ Wk,
                            const float* __restrict__ Wv, ushort* __restrict__ Wcb) {
    int row = blockIdx.x, c = threadIdx.x;
    float v;
    if (row < 32)      v = Wq[row * 256 + c];
    else if (row < 64) v = Wk[(row - 32) * 256 + c];
    else               v = Wv[(row - 64) * 256 + c];
    Wcb[row * 256 + c] = f2bf(v);
}

// ---------------- fused proj: x -> (transpose in LDS) -> Q,K,V --------------
// grid 512 = 4b x 128 n-tiles(32). Block 256 thr = 4 waves; 10 MFMA chains
// (Q, K, V0..V7) distributed cc = w, w+4, w+8. Q pre-scaled by log2(e).
__global__ __launch_bounds__(256)
void fproj_kernel(const float* __restrict__ x, const ushort* __restrict__ Wcb,
                  const float* __restrict__ bq, const float* __restrict__ bk,
                  const float* __restrict__ bv,
                  ushort* __restrict__ qbuf, ushort* __restrict__ kbuf,
                  ushort* __restrict__ vbuf) {
    __shared__ ushort xt[32 * 264];   // [n][c] bf16, stride 264 (16B-aligned rows)
    const int tid = threadIdx.x;
    const int b = blockIdx.x >> 7;
    const int n0 = (blockIdx.x & 127) << 5;

    const float* xb = x + (((size_t)b) << 20) + n0;   // b*256*4096
    #pragma unroll
    for (int i = 0; i < 8; ++i) {
        int task = tid + (i << 8);
        int c = task >> 3, seg = task & 7;
        float4 v = *(const float4*)(xb + (size_t)c * 4096 + seg * 4);
        xt[(seg * 4 + 0) * 264 + c] = f2bf(v.x);
        xt[(seg * 4 + 1) * 264 + c] = f2bf(v.y);
        xt[(seg * 4 + 2) * 264 + c] = f2bf(v.z);
        xt[(seg * 4 + 3) * 264 + c] = f2bf(v.w);
    }
    __syncthreads();

    const int w = tid >> 6, l = tid & 63;
    const int l31 = l & 31, hi = l >> 5;

    for (int cc = w; cc < 10; cc += 4) {
        const int wbase = (cc < 2) ? cc * 32 : (cc - 2) * 32 + 64;
        const ushort* wrow = Wcb + (size_t)(wbase + l31) * 256;
        f32x16 acc = (f32x16)0.0f;
        if (cc < 2) {
            // Q/K: A = xt rows (n), B = W rows (m); D[n][m], col=l31=m
            #pragma unroll
            for (int kk = 0; kk < 16; ++kk) {
                bf16x8 xf = *(const bf16x8*)&xt[l31 * 264 + kk * 16 + hi * 8];
                bf16x8 wf = *(const bf16x8*)&wrow[kk * 16 + hi * 8];
                acc = __builtin_amdgcn_mfma_f32_32x32x16_bf16(xf, wf, acc, 0, 0, 0);
            }
            const float bias = (cc == 0) ? bq[l31] : bk[l31];
            const float scale = (cc == 0) ? L2E : 1.0f;
            ushort* dst = (cc == 0) ? qbuf : kbuf;
            #pragma unroll
            for (int r = 0; r < 16; ++r) {
                int n = n0 + ROWPAT(r, hi);
                dst[((size_t)((b << 12) + n)) * 32 + l31] = f2bf((acc[r] + bias) * scale);
            }
        } else {
            // V: A = W rows (c), B = xt rows (n); D[c][n], col=l31=n
            #pragma unroll
            for (int kk = 0; kk < 16; ++kk) {
                bf16x8 wf = *(const bf16x8*)&wrow[kk * 16 + hi * 8];
                bf16x8 xf = *(const bf16x8*)&xt[l31 * 264 + kk * 16 + hi * 8];
                acc = __builtin_amdgcn_mfma_f32_32x32x16_bf16(wf, xf, acc, 0, 0, 0);
            }
            #pragma unroll
            for (int r = 0; r < 16; ++r) {
                int c = (wbase - 64) + ROWPAT(r, hi);
                vbuf[((size_t)(b * 256 + c)) * 4096 + n0 + l31] = f2bf(acc[r] + bv[c]);
            }
        }
    }
}

// ---------------- attention v7b: key-split waves, zero exp duplication ------
// grid 512 (XCD-clustered) = 4b x 128 qtiles(32q); block 256 = 4 waves.
// wave (kh=w>>1, cp=w&1) owns keys kh*32+cp*16..+15 of each 64-key tile:
// 2 QK MFMA (dup x2 per kh), exp/pack its 8 S values ONCE (exp2f — compiler
// handles the v_exp trans-op wait-state; R9's inline-asm exp violated it),
// PV over its 16 keys for ALL 256 channels (acc[8]). 3-pass LDS combine.
#define KSTR 36
#define VSTR 66
__global__ __launch_bounds__(256, 2)
void attn_kernel(const ushort* __restrict__ qbuf, const ushort* __restrict__ kbuf,
                 const ushort* __restrict__ vbuf, const float* __restrict__ x,
                 const float* __restrict__ gammap, float* __restrict__ out) {
    __shared__ ushort klds[2][64 * KSTR];   // 9 KB
    __shared__ ushort vlds[2][256 * VSTR];  // 66 KB (reused as 64KB f32 scratch)
    __shared__ float  dlds[2][2][32];

    const int tid = threadIdx.x;
    const int bid = blockIdx.x;
    const int work = (bid & 7) * 64 + (bid >> 3);   // XCD-cluster
    const int b = work >> 7;
    const int qbase = (work & 127) << 5;
    const int w = tid >> 6, l = tid & 63;
    const int l31 = l & 31, hi = l >> 5;
    const int kh = w >> 1, cp = w & 1;
    const int cps = __builtin_amdgcn_readfirstlane(cp);

    const ushort* kb = kbuf + ((size_t)b << 12) * 32;
    const ushort* vb = vbuf + ((size_t)b << 8) * 4096;

    // Q B-frags (col=q=l31, k = 16*kst + 8*hi + j); Q pre-scaled by log2(e)
    const ushort* qrow = qbuf + ((size_t)((b << 12) + qbase + l31)) * 32;
    const bf16x8 qf0 = *(const bf16x8*)&qrow[hi * 8];
    const bf16x8 qf1 = *(const bf16x8*)&qrow[16 + hi * 8];

    f32x16 acc[8];
    #pragma unroll
    for (int ch = 0; ch < 8; ++ch) acc[ch] = (f32x16)0.0f;
    float dsum = 0.f;

    // staging (256 thr): V 256x64 (32KB) via 8 uint4, K 64x32 (4KB) via 1 uint4
    const int vc = tid >> 3, vs = tid & 7;
    const int krow = tid >> 2, kseg = tid & 3;
    const ushort* vsrc = vb + (size_t)vc * 4096 + vs * 8;
    const ushort* ksrc = kb + (size_t)krow * 32 + kseg * 8;
    uint4 vreg[8], kreg;

    // prologue: stage tile 0 -> buf 0
    #pragma unroll
    for (int i = 0; i < 8; ++i)
        vreg[i] = *(const uint4*)(vsrc + (size_t)i * 32 * 4096);
    kreg = *(const uint4*)ksrc;
    #pragma unroll
    for (int i = 0; i < 8; ++i)
        *(uint4*)&vlds[0][(vc + 32 * i) * VSTR + vs * 8] = vreg[i];
    *(uint4*)&klds[0][krow * KSTR + kseg * 8] = kreg;
    __syncthreads();

    const int vcol = kh * 32 + cp * 16 + hi * 8;   // this wave's 16-key V column
    const int krow_a = (kh * 32 + l31) * KSTR;

    for (int it = 0; it < 64; ++it) {
        const int cur = it & 1;
        // issue prefetch for tile it+1
        if (it < 63) {
            const size_t m0 = (size_t)(it + 1) << 6;
            #pragma unroll
            for (int i = 0; i < 8; ++i)
                vreg[i] = *(const uint4*)(vsrc + (size_t)i * 32 * 4096 + m0);
            kreg = *(const uint4*)(ksrc + (m0 << 5));
        }

        // QK^T swapped: sT[key][q], keys = kh*32 + ROWPAT(r,hi)
        bf16x8 kf0 = *(const bf16x8*)&klds[cur][krow_a + hi * 8];
        bf16x8 kf1 = *(const bf16x8*)&klds[cur][krow_a + 16 + hi * 8];
        f32x16 sT = __builtin_amdgcn_mfma_f32_32x32x16_bf16(kf0, qf0, (f32x16)0.0f, 0, 0, 0);
        sT = __builtin_amdgcn_mfma_f32_32x32x16_bf16(kf1, qf1, sT, 0, 0, 0);

        // exp only THIS wave's 8 values (uniform branch, static indices)
        float p[8];
        if (cps) {
            p[0] = exp2f(sT[8]);  p[1] = exp2f(sT[9]);  p[2] = exp2f(sT[10]); p[3] = exp2f(sT[11]);
            p[4] = exp2f(sT[12]); p[5] = exp2f(sT[13]); p[6] = exp2f(sT[14]); p[7] = exp2f(sT[15]);
        } else {
            p[0] = exp2f(sT[0]);  p[1] = exp2f(sT[1]);  p[2] = exp2f(sT[2]);  p[3] = exp2f(sT[3]);
            p[4] = exp2f(sT[4]);  p[5] = exp2f(sT[5]);  p[6] = exp2f(sT[6]);  p[7] = exp2f(sT[7]);
        }
        dsum += ((p[0] + p[1]) + (p[2] + p[3])) + ((p[4] + p[5]) + (p[6] + p[7]));
        bf16x8 pf = packP(p[0], p[1], p[2], p[3], p[4], p[5], p[6], p[7]);

        // PV: 16 keys x all 256 channels; acc^T[c][q]
        __builtin_amdgcn_s_setprio(1);
        #pragma unroll
        for (int ch = 0; ch < 8; ++ch) {
            bf16x8 vfa = *(const bf16x8*)&vlds[cur][(ch * 32 + l31) * VSTR + vcol];
            acc[ch] = __builtin_amdgcn_mfma_f32_32x32x16_bf16(vfa, pf, acc[ch], 0, 0, 0);
        }
        __builtin_amdgcn_s_setprio(0);

        // write prefetched tile to the other buffer
        if (it < 63) {
            const int nb = cur ^ 1;
            #pragma unroll
            for (int i = 0; i < 8; ++i)
                *(uint4*)&vlds[nb][(vc + 32 * i) * VSTR + vs * 8] = vreg[i];
            *(uint4*)&klds[nb][krow * KSTR + kseg * 8] = kreg;
        }
        __syncthreads();
    }

    // ---- combine 4 partial accumulators + epilogue ----
    const float gam = gammap[0];
    float dall = dsum + __shfl_xor(dsum, 32);
    if (l < 32) dlds[kh][cp][l31] = dall;
    float* scr = (float*)&vlds[0][0];   // 64 KB scratch
    __syncthreads();
    if (kh == 1) {
        #pragma unroll
        for (int ch = 0; ch < 8; ++ch)
            #pragma unroll
            for (int r = 0; r < 16; ++r)
                scr[(((cp * 8 + ch) * 16 + r) << 6) + l] = acc[ch][r];
    }
    __syncthreads();
    if (kh == 0) {
        #pragma unroll
        for (int ch = 0; ch < 8; ++ch)
            #pragma unroll
            for (int r = 0; r < 16; ++r)
                acc[ch][r] += scr[(((cp * 8 + ch) * 16 + r) << 6) + l];
    }
    __syncthreads();
    if (kh == 0 && cp == 1) {
        #pragma unroll
        for (int ch = 0; ch < 8; ++ch)
            #pragma unroll
            for (int r = 0; r < 16; ++r)
                scr[((ch * 16 + r) << 6) + l] = acc[ch][r];
    }
    __syncthreads();
    if (kh == 0 && cp == 0) {
        #pragma unroll
        for (int ch = 0; ch < 8; ++ch)
            #pragma unroll
            for (int r = 0; r < 16; ++r) {
                float o = acc[ch][r] + scr[((ch * 16 + r) << 6) + l];
                scr[((ch * 16 + r) << 6) + l] = o;
            }
    }
    __syncthreads();
    const float denom = dlds[0][0][l31] + dlds[0][1][l31] + dlds[1][0][l31] + dlds[1][1][l31];
    const float ginv = gam / denom;
    const float* xb2 = x + (((size_t)b) << 8) * 4096;
    float* ob = out + (((size_t)b) << 8) * 4096;
    const int q = qbase + l31;
    #pragma unroll
    for (int j = 0; j < 2; ++j) {
        const int ch = w * 2 + j;
        #pragma unroll
        for (int r = 0; r < 16; ++r) {
            int c = ch * 32 + ROWPAT(r, hi);
            float o = scr[((ch * 16 + r) << 6) + l];
            size_t idx = (size_t)c * 4096 + q;
            ob[idx] = o * ginv + xb2[idx];
        }
    }
}

extern "C" void kernel_launch(void* const* d_in, const int* in_sizes, int n_in,
                              void* d_out, int out_size, void* d_ws, size_t ws_size,
                              hipStream_t stream) {
    (void)in_sizes; (void)n_in; (void)out_size; (void)ws_size;
    const float* x     = (const float*)d_in[0];
    const float* Wq    = (const float*)d_in[1];
    const float* bq    = (const float*)d_in[2];
    const float* Wk    = (const float*)d_in[3];
    const float* bk    = (const float*)d_in[4];
    const float* Wv    = (const float*)d_in[5];
    const float* bv    = (const float*)d_in[6];
    const float* gamma = (const float*)d_in[7];
    float* out = (float*)d_out;

    char* ws = (char*)d_ws;
    ushort* Wcb  = (ushort*)(ws + WCATB_OFF);
    ushort* qbuf = (ushort*)(ws + QBUF_OFF);
    ushort* kbuf = (ushort*)(ws + KBUF_OFF);
    ushort* vbuf = (ushort*)(ws + VBUF_OFF);

    prep_kernel<<<320, 256, 0, stream>>>(Wq, Wk, Wv, Wcb);
    fproj_kernel<<<512, 256, 0, stream>>>(x, Wcb, bq, bk, bv, qbuf, kbuf, vbuf);
    attn_kernel<<<512, 256, 0, stream>>>(qbuf, kbuf, vbuf, x, gamma, out);
}